// Round 18
// baseline (128.405 us; speedup 1.0000x reference)
//
#include <hip/hip_runtime.h>
#include <hip/hip_bf16.h>

typedef unsigned short u16;
typedef __attribute__((ext_vector_type(8))) short short8;
typedef __attribute__((ext_vector_type(4))) float f32x4;
typedef __attribute__((ext_vector_type(16))) float f32x16;
typedef __attribute__((ext_vector_type(4))) unsigned short u16x4;

#define DEVINL __device__ __forceinline__

DEVINL u16 f2bf(float f) {
    union { float f; unsigned u; } x; x.f = f;
    unsigned u = x.u;
    u += 0x7fffu + ((u >> 16) & 1u);   // round-to-nearest-even
    return (u16)(u >> 16);
}

DEVINL void gload_lds16(const void* g, void* l) {
    __builtin_amdgcn_global_load_lds(
        (const __attribute__((address_space(1))) unsigned*)g,
        (__attribute__((address_space(3))) unsigned*)l, 16, 0, 0);
}

// XOR swizzle for 128B/256B-stride LDS rows: spreads 16B slots across banks.
DEVINL int swz(int row) { return (((row & 7) ^ ((row >> 3) & 7)) << 4); }

// v_permlane32_swap: after call, for lane<32: a=own a, b=partner's a;
// for lane>=32: a=partner's b, b=own b.
DEVINL void swap32(unsigned& a, unsigned& b) {
#if __has_builtin(__builtin_amdgcn_permlane32_swap)
    typedef __attribute__((ext_vector_type(2))) unsigned uv2;
    uv2 r = __builtin_amdgcn_permlane32_swap(a, b, false, false);
    a = r.x; b = r.y;
#else
    int h = ((int)(threadIdx.x & 63)) >> 5;
    unsigned pa = (unsigned)__shfl_xor((int)a, 32);
    unsigned pb = (unsigned)__shfl_xor((int)b, 32);
    unsigned na = h ? pb : a;
    unsigned nb = h ? b : pa;
    a = na; b = nb;
#endif
}

// ---------------- fused prep ----------------
// blocks 0..2047:    x fp32 -> bf16 (grid-stride float4)
// blocks 2048..5119: W_attn [1024][3072] -> waT [3072][1024] bf16
// blocks 5120..6143: W_proj [1024][1024] -> wpT [1024][1024] bf16 (only if grid=6144)
__global__ __launch_bounds__(256)
void k_prep(const float* __restrict__ x, const float* __restrict__ Wa,
            const float* __restrict__ Wp,
            u16* __restrict__ xb, u16* __restrict__ waT, u16* __restrict__ wpT) {
    __shared__ float t[32][33];
    const int blk = blockIdx.x;
    const int tid = threadIdx.x;
    if (blk < 2048) {
        int i = blk * 256 + tid;
        const int stride = 2048 * 256;
        #pragma unroll
        for (int it = 0; it < 4; it++, i += stride) {   // 2097152 float4s
            float4 v = ((const float4*)x)[i];
            u16x4 o;
            o.x = f2bf(v.x); o.y = f2bf(v.y); o.z = f2bf(v.z); o.w = f2bf(v.w);
            ((u16x4*)xb)[i] = o;
        }
    } else if (blk < 5120) {
        const int b  = blk - 2048;          // 96 x 32 blocks
        const int bx = b % 96, by = b / 96;
        const int c0 = bx * 32, r0 = by * 32;
        const int tx = tid & 31, ty = tid >> 5;
        #pragma unroll
        for (int j = 0; j < 32; j += 8)
            t[ty + j][tx] = Wa[(size_t)(r0 + ty + j) * 3072 + c0 + tx];
        __syncthreads();
        #pragma unroll
        for (int j = 0; j < 32; j += 8)
            waT[(size_t)(c0 + ty + j) * 1024 + r0 + tx] = f2bf(t[tx][ty + j]);
    } else {
        const int b  = blk - 5120;          // 32 x 32 blocks
        const int bx = b & 31, by = b >> 5;
        const int c0 = bx * 32, r0 = by * 32;
        const int tx = tid & 31, ty = tid >> 5;
        #pragma unroll
        for (int j = 0; j < 32; j += 8)
            t[ty + j][tx] = Wp[(size_t)(r0 + ty + j) * 1024 + c0 + tx];
        __syncthreads();
        #pragma unroll
        for (int j = 0; j < 32; j += 8)
            wpT[(size_t)(c0 + ty + j) * 1024 + r0 + tx] = f2bf(t[tx][ty + j]);
    }
}

// ---------------- transpose + convert (fallback path only) ----------------
__global__ void k_transpose_bf(const float* __restrict__ in, u16* __restrict__ out, int R, int C) {
    __shared__ float t[32][33];
    int c0 = blockIdx.x * 32, r0 = blockIdx.y * 32;
    int tx = threadIdx.x, ty = threadIdx.y;
    #pragma unroll
    for (int j = 0; j < 32; j += 8)
        t[ty + j][tx] = in[(size_t)(r0 + ty + j) * C + c0 + tx];
    __syncthreads();
    #pragma unroll
    for (int j = 0; j < 32; j += 8)
        out[(size_t)(c0 + ty + j) * R + r0 + tx] = f2bf(t[tx][ty + j]);
}

// ---------------- GEMM-T: 128x192, BK=64, 2-phase pipeline, 2 blocks/CU ----------------
__global__ __launch_bounds__(256, 2)
void k_gemmT(const u16* __restrict__ A, const u16* __restrict__ BT,
             u16* __restrict__ C, int N, int K) {
    __shared__ char lds[2 * 40960];    // per buf: A @0 (16KB, 128 rows), B @16384 (24KB, 192 rows)

    const int tid  = threadIdx.x;
    const int lane = tid & 63;
    const int lo   = lane & 15;
    const int hi   = lane >> 4;
    const int wave = tid >> 6;
    const int wm   = wave >> 1;        // 0..1 (64-row band)
    const int wn   = wave & 1;         // 0..1 (96-col band)

    const int gx   = gridDim.x;
    const int nwg  = gx * gridDim.y;
    const int orig = blockIdx.y * gx + blockIdx.x;
    const int wg   = (orig & 7) * (nwg >> 3) + (orig >> 3);
    const long row0 = (long)(wg / gx) * 128;
    const long col0 = (long)(wg % gx) * 192;

    const int NT = K >> 6;             // BK = 64

    const int srow = tid >> 3;                         // 0..31 (row within 32-row chunk)
    const int gsb  = ((tid & 7) ^ (srow & 7)) << 4;    // pre-swizzled source byte

    auto stage = [&](int t) {
        char* base = lds + (t & 1) * 40960;
        #pragma unroll
        for (int c = 0; c < 4; c++)      // A: 128 rows = 4 chunks
            gload_lds16((const char*)(A + (row0 + c * 32 + srow) * (size_t)K + t * 64) + gsb,
                        base + c * 4096 + tid * 16);
        #pragma unroll
        for (int c = 0; c < 6; c++)      // B: 192 rows = 6 chunks
            gload_lds16((const char*)(BT + (col0 + c * 32 + srow) * (size_t)K + t * 64) + gsb,
                        base + 16384 + c * 4096 + tid * 16);
    };

    f32x4 acc[4][6] = {};

    stage(0);
    asm volatile("s_waitcnt vmcnt(0)" ::: "memory");
    __builtin_amdgcn_s_barrier();

    for (int t = 0; t < NT; t++) {
        if (t + 1 < NT) stage(t + 1);               // issue early: hides under MFMA
        const char* ab = lds + (t & 1) * 40960;
        const char* bb = ab + 16384;
        short8 af[2][4], bf[2][6];
        #pragma unroll
        for (int kk = 0; kk < 2; kk++) {
            #pragma unroll
            for (int m = 0; m < 4; m++) {
                int r = wm * 64 + m * 16 + lo;      // 0..127
                af[kk][m] = *(const short8*)(ab + r * 128 + ((kk * 64 + hi * 16) ^ ((r & 7) << 4)));
            }
            #pragma unroll
            for (int n = 0; n < 6; n++) {
                int r = wn * 96 + n * 16 + lo;      // 0..191
                bf[kk][n] = *(const short8*)(bb + r * 128 + ((kk * 64 + hi * 16) ^ ((r & 7) << 4)));
            }
        }
        #pragma unroll
        for (int m = 0; m < 4; m++)
            #pragma unroll
            for (int n = 0; n < 6; n++)
                acc[m][n] = __builtin_amdgcn_mfma_f32_16x16x32_bf16(af[0][m], bf[0][n], acc[m][n], 0, 0, 0);
        if (t + 1 < NT) {
            asm volatile("s_waitcnt vmcnt(0)" ::: "memory");   // t+1 resident
            __builtin_amdgcn_s_barrier();                      // all reads of buf[t] done
        }
        #pragma unroll
        for (int m = 0; m < 4; m++)
            #pragma unroll
            for (int n = 0; n < 6; n++)
                acc[m][n] = __builtin_amdgcn_mfma_f32_16x16x32_bf16(af[1][m], bf[1][n], acc[m][n], 0, 0, 0);
    }

    // ---- epilogue (bf16 out) ----
    #pragma unroll
    for (int m = 0; m < 4; m++)
        #pragma unroll
        for (int n = 0; n < 6; n++)
            #pragma unroll
            for (int r = 0; r < 4; r++) {
                long row = row0 + wm * 64 + m * 16 + hi * 4 + r;
                long col = col0 + wn * 96 + n * 16 + lo;
                C[row * (size_t)N + col] = f2bf(acc[m][n][r]);
            }
}

// ---------------- GEMM: 128x128, BK=64, 2-phase pipeline (R8) + kk-split ----------------
template<bool OUT_BF16>
__global__ __launch_bounds__(256, 2)
void k_gemm2(const u16* __restrict__ A, const u16* __restrict__ BT,
             void* __restrict__ C, int N, int K) {
    __shared__ char lds[2 * 32768];    // per buf: A @0 (16KB), B @16384 (16KB)

    const int tid  = threadIdx.x;
    const int lane = tid & 63;
    const int lo   = lane & 15;
    const int hi   = lane >> 4;
    const int wave = tid >> 6;
    const int wm   = wave >> 1;
    const int wn   = wave & 1;

    const int gx   = gridDim.x;
    const int nwg  = gx * gridDim.y;
    const int orig = blockIdx.y * gx + blockIdx.x;
    const int wg   = (orig & 7) * (nwg >> 3) + (orig >> 3);
    const long row0 = (long)(wg / gx) * 128;
    const long col0 = (long)(wg % gx) * 128;

    const int NT = K >> 6;             // BK = 64

    const int srow = tid >> 3;                         // 0..31 (row within 32-row chunk)
    const int gsb  = ((tid & 7) ^ (srow & 7)) << 4;    // pre-swizzled source byte

    auto stage = [&](int t) {
        char* base = lds + (t & 1) * 32768;
        #pragma unroll
        for (int c = 0; c < 4; c++)
            gload_lds16((const char*)(A + (row0 + c * 32 + srow) * (size_t)K + t * 64) + gsb,
                        base + c * 4096 + tid * 16);
        #pragma unroll
        for (int c = 0; c < 4; c++)
            gload_lds16((const char*)(BT + (col0 + c * 32 + srow) * (size_t)K + t * 64) + gsb,
                        base + 16384 + c * 4096 + tid * 16);
    };

    f32x4 acc[4][4] = {};

    stage(0);
    asm volatile("s_waitcnt vmcnt(0)" ::: "memory");
    __builtin_amdgcn_s_barrier();

    for (int t = 0; t < NT; t++) {
        if (t + 1 < NT) stage(t + 1);               // issue early: hides under MFMA
        const char* ab = lds + (t & 1) * 32768;
        const char* bb = ab + 16384;
        short8 af[2][4], bf[2][4];
        #pragma unroll
        for (int kk = 0; kk < 2; kk++) {
            #pragma unroll
            for (int m = 0; m < 4; m++) {
                int r = wm * 64 + m * 16 + lo;
                af[kk][m] = *(const short8*)(ab + r * 128 + ((kk * 64 + hi * 16) ^ ((r & 7) << 4)));
            }
            #pragma unroll
            for (int n = 0; n < 4; n++) {
                int r = wn * 64 + n * 16 + lo;
                bf[kk][n] = *(const short8*)(bb + r * 128 + ((kk * 64 + hi * 16) ^ ((r & 7) << 4)));
            }
        }
        #pragma unroll
        for (int m = 0; m < 4; m++)
            #pragma unroll
            for (int n = 0; n < 4; n++)
                acc[m][n] = __builtin_amdgcn_mfma_f32_16x16x32_bf16(af[0][m], bf[0][n], acc[m][n], 0, 0, 0);
        if (t + 1 < NT) {
            asm volatile("s_waitcnt vmcnt(0)" ::: "memory");   // t+1 resident
            __builtin_amdgcn_s_barrier();                      // all reads of buf[t] done
        }
        #pragma unroll
        for (int m = 0; m < 4; m++)
            #pragma unroll
            for (int n = 0; n < 4; n++)
                acc[m][n] = __builtin_amdgcn_mfma_f32_16x16x32_bf16(af[1][m], bf[1][n], acc[m][n], 0, 0, 0);
    }

    #pragma unroll
    for (int m = 0; m < 4; m++)
        #pragma unroll
        for (int n = 0; n < 4; n++)
            #pragma unroll
            for (int r = 0; r < 4; r++) {
                long row = row0 + wm * 64 + m * 16 + hi * 4 + r;
                long col = col0 + wn * 64 + n * 16 + lo;
                if constexpr (OUT_BF16)
                    ((u16*)C)[row * (size_t)N + col] = f2bf(acc[m][n][r]);
                else
                    ((float*)C)[row * (size_t)N + col] = acc[m][n][r];
            }
}

// ---------------- Flash attention v6: KVBLK=128 (halved per-tile fixed costs) ----------
// grid: 1024 blocks (8 qi x 128 bh), longest-first. Block = 4 waves x 32 q-rows = 128 q.
// Per buf: K 16KB ([128 kv][64 d], 128B swz rows), V 16KB ([64 d][128 kv], 256B swz rows).
// Per tile: barrier -> ISSUE K gload(t+1) + V reg-loads(t+1) -> compute(t) -> vmcnt(0)
// -> ds_write V(t+1). T5 setprio around MFMA clusters.
#define SCALE_L2E 0.18033688011112042f  // (1/sqrt(64)) * log2(e)

__global__ __launch_bounds__(256, 2)
void k_attn(const u16* __restrict__ qkv, u16* __restrict__ y) {
    constexpr int S = 1024, E = 1024, TE = 3072;
    __shared__ char alds[2 * 32768];   // per buf: K @0 (16KB), V @16384 (16KB)

    const int tid  = threadIdx.x;
    const int lane = tid & 63;
    const int l31  = lane & 31;
    const int hA   = lane >> 5;
    const int wave = tid >> 6;

    const int qi = 7 - (int)(blockIdx.x >> 7);   // longest first
    const int bh = blockIdx.x & 127;
    const int b  = bh >> 4;
    const int h  = bh & 15;
    const int q0 = qi * 128;
    const size_t rowbase = (size_t)b * S;
    const int qg = q0 + wave * 32 + l31;         // this lane's q-row

    short8 qf[4];
    {
        const u16* qp = qkv + (rowbase + qg) * TE + h * 64 + hA * 8;
        #pragma unroll
        for (int kd = 0; kd < 4; kd++) qf[kd] = *(const short8*)(qp + kd * 16);
    }

    f32x16 o0 = {}, o1 = {};
    float ms = -1e30f, lsum = 0.f;

    const int kr0 = (wave << 3) + (lane >> 3);   // K stage row base (0..31)
    const int kcb = (lane & 7) * 16;
    const int vkv = (tid >> 3) * 4;              // V rows vkv..vkv+3 (0..124)
    const int vdc = (tid & 7) * 8;               // V d-chunk

    // issue: K direct-to-LDS (4 gloads) + V global->reg (4 rows)
    auto issue = [&](int t, short8& va0, short8& va1, short8& va2, short8& va3) {
        char* base = alds + (t & 1) * 32768;
        const int kv0 = t * 128;
        #pragma unroll
        for (int it = 0; it < 4; it++) {
            int r = kr0 + it * 32;               // 0..127
            const char* src = (const char*)qkv
                + (((rowbase + kv0 + r) * TE + E + h * 64) << 1) + (kcb ^ swz(r));
            gload_lds16(src, base + wave * 1024 + it * 4096);
        }
        const u16* vsrc = qkv + (rowbase + kv0 + vkv) * TE + 2 * E + h * 64 + vdc;
        va0 = *(const short8*)vsrc;
        va1 = *(const short8*)(vsrc + TE);
        va2 = *(const short8*)(vsrc + 2 * TE);
        va3 = *(const short8*)(vsrc + 3 * TE);
    };
    // write: V regs -> swizzled LDS (256B rows); caller has vmcnt(0)'d
    auto writeV = [&](int t, short8 va0, short8 va1, short8 va2, short8 va3) {
        char* base = alds + (t & 1) * 32768 + 16384;
        #pragma unroll
        for (int j = 0; j < 8; j++) {
            int d  = vdc + j;
            int sw = swz(d);
            unsigned w01 = (unsigned)(u16)va0[j] | ((unsigned)(u16)va1[j] << 16);
            unsigned w23 = (unsigned)(u16)va2[j] | ((unsigned)(u16)va3[j] << 16);
            *(unsigned*)(base + d * 256 + ((vkv * 2) ^ sw))     = w01;
            *(unsigned*)(base + d * 256 + ((vkv * 2 + 4) ^ sw)) = w23;
        }
    };

    const int ntiles = qi + 1;
    {   // prologue: tile 0 staged fully
        short8 a0, a1, a2, a3;
        issue(0, a0, a1, a2, a3);
        asm volatile("s_waitcnt vmcnt(0)" ::: "memory");
        writeV(0, a0, a1, a2, a3);
    }
    for (int t = 0; t < ntiles; ++t) {
        __syncthreads();                       // buf[t] resident (K vmcnt'd, V lgkm-drained)
        short8 n0, n1, n2, n3;
        const bool more = (t + 1 < ntiles);
        if (more) issue(t + 1, n0, n1, n2, n3);

        const char* Kt = alds + (t & 1) * 32768;
        const char* Vt = Kt + 16384;
        const int kv0 = t * 128;

        const bool active = (kv0 <= q0 + wave * 32 + 31);   // wave-uniform
        if (active) {
            f32x16 s0 = {}, s1 = {}, s2 = {}, s3 = {};
            __builtin_amdgcn_s_setprio(1);
            #pragma unroll
            for (int kd = 0; kd < 4; kd++) {
                const int kb = kd * 32 + hA * 16;
                #define QK(SV, KS) { int r = (KS) * 32 + l31;                                 \
                    short8 ka = *(const short8*)(Kt + r * 128 + (kb ^ swz(r)));               \
                    SV = __builtin_amdgcn_mfma_f32_32x32x16_bf16(ka, qf[kd], SV, 0, 0, 0); }
                QK(s0, 0) QK(s1, 1) QK(s2, 2) QK(s3, 3)
                #undef QK
            }
            __builtin_amdgcn_s_setprio(0);

            if (kv0 + 127 > q0 + wave * 32) {   // diagonal tile only
                #pragma unroll
                for (int r = 0; r < 16; r++) {
                    int kvr = kv0 + ((r & 3) + 8 * (r >> 2) + 4 * hA);
                    if (kvr > qg)       s0[r] = -1e30f;
                    if (kvr + 32 > qg)  s1[r] = -1e30f;
                    if (kvr + 64 > qg)  s2[r] = -1e30f;
                    if (kvr + 96 > qg)  s3[r] = -1e30f;
                }
            }

            float pm = s0[0];
            #pragma unroll
            for (int r = 1; r < 16; r++) pm = fmaxf(pm, s0[r]);
            #pragma unroll
            for (int r = 0; r < 16; r++) pm = fmaxf(fmaxf(pm, s1[r]), fmaxf(s2[r], s3[r]));
            pm = fmaxf(pm, __shfl_xor(pm, 32));
            float pms = pm * SCALE_L2E;
            if (__any(pms - ms > 8.0f)) {
                float msn = fmaxf(ms, pms);
                float alpha = exp2f(ms - msn);
                ms = msn;
                lsum *= alpha;
                #pragma unroll
                for (int r = 0; r < 16; r++) { o0[r] *= alpha; o1[r] *= alpha; }
            }

            float part = 0.f;
            #pragma unroll
            for (int r = 0; r < 16; r++) {
                float p0 = exp2f(s0[r] * SCALE_L2E - ms);
                float p1 = exp2f(s1[r] * SCALE_L2E - ms);
                float p2 = exp2f(s2[r] * SCALE_L2E - ms);
                float p3 = exp2f(s3[r] * SCALE_L2E - ms);
                s0[r] = p0; s1[r] = p1; s2[r] = p2; s3[r] = p3;
                part += (p0 + p1) + (p2 + p3);
            }
            lsum += part + __shfl_xor(part, 32);

            unsigned w0[8], w1[8], w2[8], w3[8];
            #pragma unroll
            for (int j = 0; j < 8; j++) {
                asm("v_cvt_pk_bf16_f32 %0, %1, %2" : "=v"(w0[j]) : "v"(s0[2 * j]), "v"(s0[2 * j + 1]));
                asm("v_cvt_pk_bf16_f32 %0, %1, %2" : "=v"(w1[j]) : "v"(s1[2 * j]), "v"(s1[2 * j + 1]));
                asm("v_cvt_pk_bf16_f32 %0, %1, %2" : "=v"(w2[j]) : "v"(s2[2 * j]), "v"(s2[2 * j + 1]));
                asm("v_cvt_pk_bf16_f32 %0, %1, %2" : "=v"(w3[j]) : "v"(s3[2 * j]), "v"(s3[2 * j + 1]));
            }

            __builtin_amdgcn_s_setprio(1);
            #define PV_TILE(W, ST)                                                              \
            {                                                                                   \
                _Pragma("unroll")                                                               \
                for (int kkl = 0; kkl < 2; kkl++) {                                             \
                    unsigned a  = W[4 * kkl],     bsw = W[4 * kkl + 2];                         \
                    unsigned a2 = W[4 * kkl + 1], b2  = W[4 * kkl + 3];                         \
                    swap32(a, bsw); swap32(a2, b2);                                             \
                    union { int4 i; short8 s; } u;                                              \
                    u.i = make_int4((int)a, (int)a2, (int)bsw, (int)b2);                        \
                    {                                                                           \
                        int row = l31;                                                          \
                        short8 va = *(const short8*)(Vt + row * 256                             \
                                      + (((ST) * 64 + kkl * 32 + hA * 16) ^ swz(row)));         \
                        o0 = __builtin_amdgcn_mfma_f32_32x32x16_bf16(va, u.s, o0, 0, 0, 0);     \
                    }                                                                           \
                    {                                                                           \
                        int row = 32 + l31;                                                     \
                        short8 va = *(const short8*)(Vt + row * 256                             \
                                      + (((ST) * 64 + kkl * 32 + hA * 16) ^ swz(row)));         \
                        o1 = __builtin_amdgcn_mfma_f32_32x32x16_bf16(va, u.s, o1, 0, 0, 0);     \
                    }                                                                           \
                }                                                                               \
            }
            PV_TILE(w0, 0)
            PV_TILE(w1, 1)
            PV_TILE(w2, 2)
            PV_TILE(w3, 3)
            #undef PV_TILE
            __builtin_amdgcn_s_setprio(0);
        }

        if (more) {
            asm volatile("s_waitcnt vmcnt(0)" ::: "memory");   // V regs + K gload arrived
            writeV(t + 1, n0, n1, n2, n3);                     // lgkm drained by next barrier
        }
    }

    // ---- epilogue: normalize, transpose O^T -> O via LDS, store bf16 ----
    __syncthreads();   // all tiles done reading K/V buffers
    float rinv = 1.0f / lsum;
    char* Ot = alds + wave * 4096;     // 32 rows x 64 d per wave (4KB), wave-private
    const int X = (l31 & 7) << 4;
    #pragma unroll
    for (int rq = 0; rq < 4; rq++) {
        u16x4 pk0, pk1;
        #pragma unroll
        for (int j = 0; j < 4; j++) {
            pk0[j] = f2bf(o0[4 * rq + j] * rinv);    // d = 8*rq + 4*hA + j
            pk1[j] = f2bf(o1[4 * rq + j] * rinv);    // d = 32 + 8*rq + 4*hA + j
        }
        *(u16x4*)(Ot + l31 * 128 + ((16 * rq + 8 * hA) ^ X))      = pk0;
        *(u16x4*)(Ot + l31 * 128 + ((64 + 16 * rq + 8 * hA) ^ X)) = pk1;
    }
    __syncthreads();
    #pragma unroll
    for (int p = 0; p < 4; p++) {
        int row = p * 8 + (lane >> 3);               // 0..31 within wave's tile
        int cc  = lane & 7;                          // 16B chunk (8 d-elems)
        short8 vv = *(const short8*)(Ot + row * 128 + ((cc * 16) ^ ((row & 7) << 4)));
        *(short8*)(y + (rowbase + q0 + wave * 32 + row) * E + h * 64 + cc * 8) = vv;
    }
}

// ---------------- launch ----------------
extern "C" void kernel_launch(void* const* d_in, const int* in_sizes, int n_in,
                              void* d_out, int out_size, void* d_ws, size_t ws_size,
                              hipStream_t stream) {
    const float* x     = (const float*)d_in[0];   // [8,1024,1024]
    const float* Wattn = (const float*)d_in[1];   // [1024,3072]
    const float* Wproj = (const float*)d_in[2];   // [1024,1024]
    float* out = (float*)d_out;                   // [8,1024,1024] fp32

    char* ws = (char*)d_ws;
    u16* buf0 = (u16*)ws;                                  // x_bf16, later y_bf16 (16.78 MB)
    u16* wT   = (u16*)(ws + 16777216);                     // W_attn^T bf16 (6.29 MB)
    u16* qkv  = (u16*)(ws + 16777216 + 6291456);           // [8192][3072] bf16 (50.3 MB)
    const size_t wpT_off = 16777216ull + 6291456 + 50331648;
    const bool fused_wp = ws_size >= wpT_off + 2097152;    // room for W_proj^T?
    u16* wpT  = fused_wp ? (u16*)(ws + wpT_off) : wT;      // fallback: reuse wT

    // fused prep: x->bf16 + W_attn^T (+ W_proj^T when buffer space allows)
    k_prep<<<fused_wp ? 6144 : 5120, 256, 0, stream>>>(x, Wattn, Wproj, buf0, wT, wpT);
    // qkv = x @ W_attn   (bf16 out): 128x192 tile, grid 16x64 = 1024 wgs, 2 rounds exact
    k_gemmT<<<dim3(3072 / 192, 8192 / 128), 256, 0, stream>>>(buf0, wT, qkv, 3072, 1024);
    if (!fused_wp) {
        // fallback: W_proj^T -> wT after GEMM1 (old R14 path)
        k_transpose_bf<<<dim3(1024 / 32, 1024 / 32), dim3(32, 8), 0, stream>>>(Wproj, wT, 1024, 1024);
    }
    // flash attention -> y (reuses buf0)
    k_attn<<<dim3(1024), 256, 0, stream>>>(qkv, buf0);
    // out = y @ W_proj  (fp32 out): 128x128 2-phase, grid 8x64 = 512 wgs
    k_gemm2<false><<<dim3(1024 / 128, 8192 / 128), 256, 0, stream>>>(buf0, wpT, out, 1024, 1024);
}

// Round 19
// 123.879 us; speedup vs baseline: 1.0365x; 1.0365x over previous
//
#include <hip/hip_runtime.h>
#include <hip/hip_bf16.h>

typedef unsigned short u16;
typedef __attribute__((ext_vector_type(8))) short short8;
typedef __attribute__((ext_vector_type(4))) float f32x4;
typedef __attribute__((ext_vector_type(16))) float f32x16;
typedef __attribute__((ext_vector_type(4))) unsigned short u16x4;

#define DEVINL __device__ __forceinline__

DEVINL u16 f2bf(float f) {
    union { float f; unsigned u; } x; x.f = f;
    unsigned u = x.u;
    u += 0x7fffu + ((u >> 16) & 1u);   // round-to-nearest-even
    return (u16)(u >> 16);
}

DEVINL void gload_lds16(const void* g, void* l) {
    __builtin_amdgcn_global_load_lds(
        (const __attribute__((address_space(1))) unsigned*)g,
        (__attribute__((address_space(3))) unsigned*)l, 16, 0, 0);
}

// XOR swizzle for 128B-stride LDS rows: spreads 16B slots across banks.
DEVINL int swz(int row) { return (((row & 7) ^ ((row >> 3) & 7)) << 4); }

// v_permlane32_swap: after call, for lane<32: a=own a, b=partner's a;
// for lane>=32: a=partner's b, b=own b.
DEVINL void swap32(unsigned& a, unsigned& b) {
#if __has_builtin(__builtin_amdgcn_permlane32_swap)
    typedef __attribute__((ext_vector_type(2))) unsigned uv2;
    uv2 r = __builtin_amdgcn_permlane32_swap(a, b, false, false);
    a = r.x; b = r.y;
#else
    int h = ((int)(threadIdx.x & 63)) >> 5;
    unsigned pa = (unsigned)__shfl_xor((int)a, 32);
    unsigned pb = (unsigned)__shfl_xor((int)b, 32);
    unsigned na = h ? pb : a;
    unsigned nb = h ? b : pa;
    a = na; b = nb;
#endif
}

// ---------------- fused prep ----------------
// blocks 0..2047:    x fp32 -> bf16 (grid-stride float4)
// blocks 2048..5119: W_attn [1024][3072] -> waT [3072][1024] bf16
// blocks 5120..6143: W_proj [1024][1024] -> wpT [1024][1024] bf16 (only if grid=6144)
__global__ __launch_bounds__(256)
void k_prep(const float* __restrict__ x, const float* __restrict__ Wa,
            const float* __restrict__ Wp,
            u16* __restrict__ xb, u16* __restrict__ waT, u16* __restrict__ wpT) {
    __shared__ float t[32][33];
    const int blk = blockIdx.x;
    const int tid = threadIdx.x;
    if (blk < 2048) {
        int i = blk * 256 + tid;
        const int stride = 2048 * 256;
        #pragma unroll
        for (int it = 0; it < 4; it++, i += stride) {   // 2097152 float4s
            float4 v = ((const float4*)x)[i];
            u16x4 o;
            o.x = f2bf(v.x); o.y = f2bf(v.y); o.z = f2bf(v.z); o.w = f2bf(v.w);
            ((u16x4*)xb)[i] = o;
        }
    } else if (blk < 5120) {
        const int b  = blk - 2048;          // 96 x 32 blocks
        const int bx = b % 96, by = b / 96;
        const int c0 = bx * 32, r0 = by * 32;
        const int tx = tid & 31, ty = tid >> 5;
        #pragma unroll
        for (int j = 0; j < 32; j += 8)
            t[ty + j][tx] = Wa[(size_t)(r0 + ty + j) * 3072 + c0 + tx];
        __syncthreads();
        #pragma unroll
        for (int j = 0; j < 32; j += 8)
            waT[(size_t)(c0 + ty + j) * 1024 + r0 + tx] = f2bf(t[tx][ty + j]);
    } else {
        const int b  = blk - 5120;          // 32 x 32 blocks
        const int bx = b & 31, by = b >> 5;
        const int c0 = bx * 32, r0 = by * 32;
        const int tx = tid & 31, ty = tid >> 5;
        #pragma unroll
        for (int j = 0; j < 32; j += 8)
            t[ty + j][tx] = Wp[(size_t)(r0 + ty + j) * 1024 + c0 + tx];
        __syncthreads();
        #pragma unroll
        for (int j = 0; j < 32; j += 8)
            wpT[(size_t)(c0 + ty + j) * 1024 + r0 + tx] = f2bf(t[tx][ty + j]);
    }
}

// ---------------- transpose + convert (fallback path only) ----------------
__global__ void k_transpose_bf(const float* __restrict__ in, u16* __restrict__ out, int R, int C) {
    __shared__ float t[32][33];
    int c0 = blockIdx.x * 32, r0 = blockIdx.y * 32;
    int tx = threadIdx.x, ty = threadIdx.y;
    #pragma unroll
    for (int j = 0; j < 32; j += 8)
        t[ty + j][tx] = in[(size_t)(r0 + ty + j) * C + c0 + tx];
    __syncthreads();
    #pragma unroll
    for (int j = 0; j < 32; j += 8)
        out[(size_t)(c0 + ty + j) * R + r0 + tx] = f2bf(t[tx][ty + j]);
}

// ---------------- GEMM-T: 128x192, BK=64, 2-phase pipeline, 2 blocks/CU ----------------
// C[M][N] = A[M][K] @ BT[N][K]^T, bf16 in, bf16 out. 4 waves (2x2), per-wave 64x96.
// dbuf 2x40KB = 80KB -> 2 blocks/CU = 160KB (full pool).
__global__ __launch_bounds__(256, 2)
void k_gemmT(const u16* __restrict__ A, const u16* __restrict__ BT,
             u16* __restrict__ C, int N, int K) {
    __shared__ char lds[2 * 40960];    // per buf: A @0 (16KB, 128 rows), B @16384 (24KB, 192 rows)

    const int tid  = threadIdx.x;
    const int lane = tid & 63;
    const int lo   = lane & 15;
    const int hi   = lane >> 4;
    const int wave = tid >> 6;
    const int wm   = wave >> 1;        // 0..1 (64-row band)
    const int wn   = wave & 1;         // 0..1 (96-col band)

    // XCD-aware bijective block swizzle (nwg % 8 == 0)
    const int gx   = gridDim.x;
    const int nwg  = gx * gridDim.y;
    const int orig = blockIdx.y * gx + blockIdx.x;
    const int wg   = (orig & 7) * (nwg >> 3) + (orig >> 3);
    const long row0 = (long)(wg / gx) * 128;
    const long col0 = (long)(wg % gx) * 192;

    const int NT = K >> 6;             // BK = 64

    const int srow = tid >> 3;                         // 0..31 (row within 32-row chunk)
    const int gsb  = ((tid & 7) ^ (srow & 7)) << 4;    // pre-swizzled source byte

    auto stage = [&](int t) {
        char* base = lds + (t & 1) * 40960;
        #pragma unroll
        for (int c = 0; c < 4; c++)      // A: 128 rows = 4 chunks
            gload_lds16((const char*)(A + (row0 + c * 32 + srow) * (size_t)K + t * 64) + gsb,
                        base + c * 4096 + tid * 16);
        #pragma unroll
        for (int c = 0; c < 6; c++)      // B: 192 rows = 6 chunks
            gload_lds16((const char*)(BT + (col0 + c * 32 + srow) * (size_t)K + t * 64) + gsb,
                        base + 16384 + c * 4096 + tid * 16);
    };

    f32x4 acc[4][6] = {};

    stage(0);
    asm volatile("s_waitcnt vmcnt(0)" ::: "memory");
    __builtin_amdgcn_s_barrier();

    for (int t = 0; t < NT; t++) {
        if (t + 1 < NT) stage(t + 1);               // issue early: hides under MFMA
        const char* ab = lds + (t & 1) * 40960;
        const char* bb = ab + 16384;
        short8 af[2][4], bf[2][6];
        #pragma unroll
        for (int kk = 0; kk < 2; kk++) {
            #pragma unroll
            for (int m = 0; m < 4; m++) {
                int r = wm * 64 + m * 16 + lo;      // 0..127
                af[kk][m] = *(const short8*)(ab + r * 128 + ((kk * 64 + hi * 16) ^ ((r & 7) << 4)));
            }
            #pragma unroll
            for (int n = 0; n < 6; n++) {
                int r = wn * 96 + n * 16 + lo;      // 0..191
                bf[kk][n] = *(const short8*)(bb + r * 128 + ((kk * 64 + hi * 16) ^ ((r & 7) << 4)));
            }
        }
        #pragma unroll
        for (int m = 0; m < 4; m++)
            #pragma unroll
            for (int n = 0; n < 6; n++)
                acc[m][n] = __builtin_amdgcn_mfma_f32_16x16x32_bf16(af[0][m], bf[0][n], acc[m][n], 0, 0, 0);
        if (t + 1 < NT) {
            asm volatile("s_waitcnt vmcnt(0)" ::: "memory");   // t+1 resident
            __builtin_amdgcn_s_barrier();                      // all reads of buf[t] done
        }
        #pragma unroll
        for (int m = 0; m < 4; m++)
            #pragma unroll
            for (int n = 0; n < 6; n++)
                acc[m][n] = __builtin_amdgcn_mfma_f32_16x16x32_bf16(af[1][m], bf[1][n], acc[m][n], 0, 0, 0);
    }

    // ---- epilogue (bf16 out) ----
    #pragma unroll
    for (int m = 0; m < 4; m++)
        #pragma unroll
        for (int n = 0; n < 6; n++)
            #pragma unroll
            for (int r = 0; r < 4; r++) {
                long row = row0 + wm * 64 + m * 16 + hi * 4 + r;
                long col = col0 + wn * 96 + n * 16 + lo;
                C[row * (size_t)N + col] = f2bf(acc[m][n][r]);
            }
}

// ---------------- GEMM: 128x128, BK=64, 2-phase pipeline (R8) + kk-split ----------------
// Used for GEMM2 (N=1024, 192 doesn't divide). Same mechanism set.
template<bool OUT_BF16>
__global__ __launch_bounds__(256, 2)
void k_gemm2(const u16* __restrict__ A, const u16* __restrict__ BT,
             void* __restrict__ C, int N, int K) {
    __shared__ char lds[2 * 32768];    // per buf: A @0 (16KB), B @16384 (16KB)

    const int tid  = threadIdx.x;
    const int lane = tid & 63;
    const int lo   = lane & 15;
    const int hi   = lane >> 4;
    const int wave = tid >> 6;
    const int wm   = wave >> 1;
    const int wn   = wave & 1;

    const int gx   = gridDim.x;
    const int nwg  = gx * gridDim.y;
    const int orig = blockIdx.y * gx + blockIdx.x;
    const int wg   = (orig & 7) * (nwg >> 3) + (orig >> 3);
    const long row0 = (long)(wg / gx) * 128;
    const long col0 = (long)(wg % gx) * 128;

    const int NT = K >> 6;             // BK = 64

    const int srow = tid >> 3;                         // 0..31 (row within 32-row chunk)
    const int gsb  = ((tid & 7) ^ (srow & 7)) << 4;    // pre-swizzled source byte

    auto stage = [&](int t) {
        char* base = lds + (t & 1) * 32768;
        #pragma unroll
        for (int c = 0; c < 4; c++)
            gload_lds16((const char*)(A + (row0 + c * 32 + srow) * (size_t)K + t * 64) + gsb,
                        base + c * 4096 + tid * 16);
        #pragma unroll
        for (int c = 0; c < 4; c++)
            gload_lds16((const char*)(BT + (col0 + c * 32 + srow) * (size_t)K + t * 64) + gsb,
                        base + 16384 + c * 4096 + tid * 16);
    };

    f32x4 acc[4][4] = {};

    stage(0);
    asm volatile("s_waitcnt vmcnt(0)" ::: "memory");
    __builtin_amdgcn_s_barrier();

    for (int t = 0; t < NT; t++) {
        if (t + 1 < NT) stage(t + 1);               // issue early: hides under MFMA
        const char* ab = lds + (t & 1) * 32768;
        const char* bb = ab + 16384;
        short8 af[2][4], bf[2][4];
        #pragma unroll
        for (int kk = 0; kk < 2; kk++) {
            #pragma unroll
            for (int m = 0; m < 4; m++) {
                int r = wm * 64 + m * 16 + lo;
                af[kk][m] = *(const short8*)(ab + r * 128 + ((kk * 64 + hi * 16) ^ ((r & 7) << 4)));
            }
            #pragma unroll
            for (int n = 0; n < 4; n++) {
                int r = wn * 64 + n * 16 + lo;
                bf[kk][n] = *(const short8*)(bb + r * 128 + ((kk * 64 + hi * 16) ^ ((r & 7) << 4)));
            }
        }
        #pragma unroll
        for (int m = 0; m < 4; m++)
            #pragma unroll
            for (int n = 0; n < 4; n++)
                acc[m][n] = __builtin_amdgcn_mfma_f32_16x16x32_bf16(af[0][m], bf[0][n], acc[m][n], 0, 0, 0);
        if (t + 1 < NT) {
            asm volatile("s_waitcnt vmcnt(0)" ::: "memory");   // t+1 resident
            __builtin_amdgcn_s_barrier();                      // all reads of buf[t] done
        }
        #pragma unroll
        for (int m = 0; m < 4; m++)
            #pragma unroll
            for (int n = 0; n < 4; n++)
                acc[m][n] = __builtin_amdgcn_mfma_f32_16x16x32_bf16(af[1][m], bf[1][n], acc[m][n], 0, 0, 0);
    }

    #pragma unroll
    for (int m = 0; m < 4; m++)
        #pragma unroll
        for (int n = 0; n < 4; n++)
            #pragma unroll
            for (int r = 0; r < 4; r++) {
                long row = row0 + wm * 64 + m * 16 + hi * 4 + r;
                long col = col0 + wn * 64 + n * 16 + lo;
                if constexpr (OUT_BF16)
                    ((u16*)C)[row * (size_t)N + col] = f2bf(acc[m][n][r]);
                else
                    ((float*)C)[row * (size_t)N + col] = acc[m][n][r];
            }
}

// ---------------- Flash attention v5 (R17 proven): swapped 32x32, dbuf K/V, T14 + T5 ----
// grid: 1024 blocks (8 qi x 128 bh), longest-first. Block = 4 waves x 32 q-rows = 128 q.
// Per tile: barrier -> ISSUE V global loads(t+1) + K gload_lds(t+1) -> compute(t)
// (HBM latency hides under compute) -> vmcnt(0) -> ds_write V(t+1).
#define SCALE_L2E 0.18033688011112042f  // (1/sqrt(64)) * log2(e)

__global__ __launch_bounds__(256, 2)
void k_attn(const u16* __restrict__ qkv, u16* __restrict__ y) {
    constexpr int S = 1024, E = 1024, TE = 3072;
    __shared__ char alds[2 * 16384];   // per buf: K @0 (8KB, [kv][d] swz), V @8192 ([d][kv] swz)

    const int tid  = threadIdx.x;
    const int lane = tid & 63;
    const int l31  = lane & 31;
    const int hA   = lane >> 5;
    const int wave = tid >> 6;

    const int qi = 7 - (int)(blockIdx.x >> 7);   // longest first
    const int bh = blockIdx.x & 127;
    const int b  = bh >> 4;
    const int h  = bh & 15;
    const int q0 = qi * 128;
    const size_t rowbase = (size_t)b * S;
    const int qg = q0 + wave * 32 + l31;         // this lane's q-row

    short8 qf[4];
    {
        const u16* qp = qkv + (rowbase + qg) * TE + h * 64 + hA * 8;
        #pragma unroll
        for (int kd = 0; kd < 4; kd++) qf[kd] = *(const short8*)(qp + kd * 16);
    }

    f32x16 o0 = {}, o1 = {};
    float ms = -1e30f, lsum = 0.f;

    const int kr0 = (wave << 3) + (lane >> 3);
    const int kcb = (lane & 7) * 16;
    const int vkv = (tid >> 3) * 2;
    const int vdc = (tid & 7) * 8;

    // issue phase: K direct-to-LDS + V global->reg (latency hides under compute)
    auto issue = [&](int t, short8& v0, short8& v1) {
        char* base = alds + (t & 1) * 16384;
        const int kv0 = t * 64;
        #pragma unroll
        for (int it = 0; it < 2; it++) {
            int r = kr0 + it * 32;
            const char* src = (const char*)qkv
                + (((rowbase + kv0 + r) * TE + E + h * 64) << 1) + (kcb ^ swz(r));
            gload_lds16(src, base + wave * 1024 + it * 4096);
        }
        const u16* vsrc = qkv + (rowbase + kv0 + vkv) * TE + 2 * E + h * 64 + vdc;
        v0 = *(const short8*)vsrc;
        v1 = *(const short8*)(vsrc + TE);
    };
    // write phase: V regs -> swizzled LDS (after compute; vmcnt(0) done by caller)
    auto writeV = [&](int t, short8 v0, short8 v1) {
        char* base = alds + (t & 1) * 16384;
        #pragma unroll
        for (int j = 0; j < 8; j++) {
            int d = vdc + j;
            unsigned val = (unsigned)(u16)v0[j] | ((unsigned)(u16)v1[j] << 16);
            *(unsigned*)(base + 8192 + d * 128 + ((vkv * 2) ^ swz(d))) = val;
        }
    };

    const int ntiles = 2 * qi + 2;
    {   // prologue: tile 0 staged fully
        short8 v0, v1;
        issue(0, v0, v1);
        asm volatile("s_waitcnt vmcnt(0)" ::: "memory");
        writeV(0, v0, v1);
    }
    for (int t = 0; t < ntiles; ++t) {
        __syncthreads();                       // buf[t] resident (K vmcnt'd, V lgkm-drained)
        short8 nv0, nv1;
        const bool more = (t + 1 < ntiles);
        if (more) issue(t + 1, nv0, nv1);      // K gload + V reg-loads in flight

        const char* Kt = alds + (t & 1) * 16384;
        const char* Vt = Kt + 8192;
        const int kv0 = t * 64;

        const bool active = (kv0 <= q0 + wave * 32 + 31);   // wave-uniform
        if (active) {
            f32x16 s0 = {}, s1 = {};
            __builtin_amdgcn_s_setprio(1);
            #pragma unroll
            for (int kd = 0; kd < 4; kd++) {
                int r0 = l31, r1 = 32 + l31;
                short8 ka0 = *(const short8*)(Kt + r0 * 128 + ((kd * 32 + hA * 16) ^ swz(r0)));
                short8 ka1 = *(const short8*)(Kt + r1 * 128 + ((kd * 32 + hA * 16) ^ swz(r1)));
                s0 = __builtin_amdgcn_mfma_f32_32x32x16_bf16(ka0, qf[kd], s0, 0, 0, 0);
                s1 = __builtin_amdgcn_mfma_f32_32x32x16_bf16(ka1, qf[kd], s1, 0, 0, 0);
            }
            __builtin_amdgcn_s_setprio(0);

            if (kv0 + 63 > q0 + wave * 32) {
                #pragma unroll
                for (int r = 0; r < 16; r++) {
                    int kvr = kv0 + ((r & 3) + 8 * (r >> 2) + 4 * hA);
                    if (kvr > qg)      s0[r] = -1e30f;
                    if (kvr + 32 > qg) s1[r] = -1e30f;
                }
            }

            float pm = s0[0];
            #pragma unroll
            for (int r = 1; r < 16; r++) pm = fmaxf(pm, s0[r]);
            #pragma unroll
            for (int r = 0; r < 16; r++) pm = fmaxf(pm, s1[r]);
            pm = fmaxf(pm, __shfl_xor(pm, 32));
            float pms = pm * SCALE_L2E;
            if (__any(pms - ms > 8.0f)) {
                float msn = fmaxf(ms, pms);
                float alpha = exp2f(ms - msn);
                ms = msn;
                lsum *= alpha;
                #pragma unroll
                for (int r = 0; r < 16; r++) { o0[r] *= alpha; o1[r] *= alpha; }
            }

            float part = 0.f;
            #pragma unroll
            for (int r = 0; r < 16; r++) {
                float p0 = exp2f(s0[r] * SCALE_L2E - ms);
                float p1 = exp2f(s1[r] * SCALE_L2E - ms);
                s0[r] = p0; s1[r] = p1;
                part += p0 + p1;
            }
            lsum += part + __shfl_xor(part, 32);

            unsigned w0[8], w1[8];
            #pragma unroll
            for (int j = 0; j < 8; j++) {
                asm("v_cvt_pk_bf16_f32 %0, %1, %2" : "=v"(w0[j]) : "v"(s0[2 * j]), "v"(s0[2 * j + 1]));
                asm("v_cvt_pk_bf16_f32 %0, %1, %2" : "=v"(w1[j]) : "v"(s1[2 * j]), "v"(s1[2 * j + 1]));
            }

            __builtin_amdgcn_s_setprio(1);
            #define PV_TILE(W, ST)                                                              \
            {                                                                                   \
                _Pragma("unroll")                                                               \
                for (int kkl = 0; kkl < 2; kkl++) {                                             \
                    unsigned a  = W[4 * kkl],     bsw = W[4 * kkl + 2];                         \
                    unsigned a2 = W[4 * kkl + 1], b2  = W[4 * kkl + 3];                         \
                    swap32(a, bsw); swap32(a2, b2);                                             \
                    union { int4 i; short8 s; } u;                                              \
                    u.i = make_int4((int)a, (int)a2, (int)bsw, (int)b2);                        \
                    {                                                                           \
                        int row = l31;                                                          \
                        short8 va = *(const short8*)(Vt + row * 128                             \
                                      + (((ST) * 64 + kkl * 32 + hA * 16) ^ swz(row)));         \
                        o0 = __builtin_amdgcn_mfma_f32_32x32x16_bf16(va, u.s, o0, 0, 0, 0);     \
                    }                                                                           \
                    {                                                                           \
                        int row = 32 + l31;                                                     \
                        short8 va = *(const short8*)(Vt + row * 128                             \
                                      + (((ST) * 64 + kkl * 32 + hA * 16) ^ swz(row)));         \
                        o1 = __builtin_amdgcn_mfma_f32_32x32x16_bf16(va, u.s, o1, 0, 0, 0);     \
                    }                                                                           \
                }                                                                               \
            }
            PV_TILE(w0, 0)
            PV_TILE(w1, 1)
            #undef PV_TILE
            __builtin_amdgcn_s_setprio(0);
        }

        if (more) {
            asm volatile("s_waitcnt vmcnt(0)" ::: "memory");   // V regs + K gload arrived
            writeV(t + 1, nv0, nv1);                           // lgkm drained by next barrier
        }
    }

    // ---- epilogue: normalize, transpose O^T -> O via LDS, store bf16 ----
    __syncthreads();   // all tiles done reading K/V buffers
    float rinv = 1.0f / lsum;
    char* Ot = alds + wave * 4096;     // 32 rows x 64 d per wave (4KB), wave-private
    const int X = (l31 & 7) << 4;
    #pragma unroll
    for (int rq = 0; rq < 4; rq++) {
        u16x4 pk0, pk1;
        #pragma unroll
        for (int j = 0; j < 4; j++) {
            pk0[j] = f2bf(o0[4 * rq + j] * rinv);    // d = 8*rq + 4*hA + j
            pk1[j] = f2bf(o1[4 * rq + j] * rinv);    // d = 32 + 8*rq + 4*hA + j
        }
        *(u16x4*)(Ot + l31 * 128 + ((16 * rq + 8 * hA) ^ X))      = pk0;
        *(u16x4*)(Ot + l31 * 128 + ((64 + 16 * rq + 8 * hA) ^ X)) = pk1;
    }
    __syncthreads();
    #pragma unroll
    for (int p = 0; p < 4; p++) {
        int row = p * 8 + (lane >> 3);               // 0..31 within wave's tile
        int cc  = lane & 7;                          // 16B chunk (8 d-elems)
        short8 vv = *(const short8*)(Ot + row * 128 + ((cc * 16) ^ ((row & 7) << 4)));
        *(short8*)(y + (rowbase + q0 + wave * 32 + row) * E + h * 64 + cc * 8) = vv;
    }
}

// ---------------- launch ----------------
extern "C" void kernel_launch(void* const* d_in, const int* in_sizes, int n_in,
                              void* d_out, int out_size, void* d_ws, size_t ws_size,
                              hipStream_t stream) {
    const float* x     = (const float*)d_in[0];   // [8,1024,1024]
    const float* Wattn = (const float*)d_in[1];   // [1024,3072]
    const float* Wproj = (const float*)d_in[2];   // [1024,1024]
    float* out = (float*)d_out;                   // [8,1024,1024] fp32

    char* ws = (char*)d_ws;
    u16* buf0 = (u16*)ws;                                  // x_bf16, later y_bf16 (16.78 MB)
    u16* wT   = (u16*)(ws + 16777216);                     // W_attn^T bf16 (6.29 MB)
    u16* qkv  = (u16*)(ws + 16777216 + 6291456);           // [8192][3072] bf16 (50.3 MB)
    const size_t wpT_off = 16777216ull + 6291456 + 50331648;
    const bool fused_wp = ws_size >= wpT_off + 2097152;    // room for W_proj^T?
    u16* wpT  = fused_wp ? (u16*)(ws + wpT_off) : wT;      // fallback: reuse wT

    // fused prep: x->bf16 + W_attn^T (+ W_proj^T when buffer space allows)
    k_prep<<<fused_wp ? 6144 : 5120, 256, 0, stream>>>(x, Wattn, Wproj, buf0, wT, wpT);
    // qkv = x @ W_attn   (bf16 out): 128x192 tile, grid 16x64 = 1024 wgs, 2 rounds exact
    k_gemmT<<<dim3(3072 / 192, 8192 / 128), 256, 0, stream>>>(buf0, wT, qkv, 3072, 1024);
    if (!fused_wp) {
        // fallback: W_proj^T -> wT after GEMM1 (old R14 path)
        k_transpose_bf<<<dim3(1024 / 32, 1024 / 32), dim3(32, 8), 0, stream>>>(Wproj, wT, 1024, 1024);
    }
    // flash attention -> y (reuses buf0)
    k_attn<<<dim3(1024), 256, 0, stream>>>(qkv, buf0);
    // out = y @ W_proj  (fp32 out): 128x128 2-phase, grid 8x64 = 512 wgs
    k_gemm2<false><<<dim3(1024 / 128, 8192 / 128), 256, 0, stream>>>(buf0, wpT, out, 1024, 1024);
}